// Round 2
// baseline (2399.256 us; speedup 1.0000x reference)
//
#include <hip/hip_runtime.h>
#include <hip/hip_bf16.h>

#define TT 200
#define NBATCH 256
#define HID 128
#define G4 512
#define VOC 50000

// xg storage type helpers (fp32 primary; bf16 only as ws-too-small fallback)
__device__ inline void xg_store(float* p, float v) { *p = v; }
__device__ inline void xg_store(__hip_bfloat16* p, float v) { *p = __float2bfloat16(v); }
__device__ inline float xg_load(const float* p) { return *p; }
__device__ inline float xg_load(const __hip_bfloat16* p) { return __bfloat162float(*p); }

// ---------------- Kernel 1: x_gates = gather(ET, seq) @ W + b ----------------
// grid 1600, block 512; 32 rows per block
template <typename XGT>
__global__ __launch_bounds__(512, 2) void k1_xgates(
    const int* __restrict__ seq,        // (T*N)
    const float* __restrict__ ET,       // (V, H)
    const float* __restrict__ W,        // (H, 4H)
    const float* __restrict__ b,        // (4H)
    XGT* __restrict__ xg)               // (T*N, 4H)
{
    const int tid = threadIdx.x;
    const int row0 = blockIdx.x * 32;
    __shared__ int idx[32];
    __shared__ __align__(16) float emb[32][HID];
    if (tid < 32) idx[tid] = seq[row0 + tid];
    __syncthreads();
    {
        const int r = tid >> 4;        // 0..31
        const int c = tid & 15;        // 16 chunks of 8 floats
        const float* src = ET + (size_t)idx[r] * HID + c * 8;
        float4 v0 = ((const float4*)src)[0];
        float4 v1 = ((const float4*)src)[1];
        ((float4*)&emb[r][c * 8])[0] = v0;
        ((float4*)&emb[r][c * 8])[1] = v1;
    }
    float wcol[HID];
    #pragma unroll
    for (int h = 0; h < HID; ++h) wcol[h] = W[(size_t)h * G4 + tid];
    const float bj = b[tid];
    __syncthreads();

    #pragma unroll 4
    for (int r = 0; r < 32; ++r) {
        float a0 = bj, a1 = 0.f, a2 = 0.f, a3 = 0.f;
        const float4* e4 = (const float4*)&emb[r][0];
        #pragma unroll
        for (int q = 0; q < 8; ++q) {
            float4 e0 = e4[q*4+0], e1 = e4[q*4+1], e2 = e4[q*4+2], e3 = e4[q*4+3];
            a0 = fmaf(e0.x, wcol[q*16+0],  a0); a1 = fmaf(e0.y, wcol[q*16+1],  a1);
            a2 = fmaf(e0.z, wcol[q*16+2],  a2); a3 = fmaf(e0.w, wcol[q*16+3],  a3);
            a0 = fmaf(e1.x, wcol[q*16+4],  a0); a1 = fmaf(e1.y, wcol[q*16+5],  a1);
            a2 = fmaf(e1.z, wcol[q*16+6],  a2); a3 = fmaf(e1.w, wcol[q*16+7],  a3);
            a0 = fmaf(e2.x, wcol[q*16+8],  a0); a1 = fmaf(e2.y, wcol[q*16+9],  a1);
            a2 = fmaf(e2.z, wcol[q*16+10], a2); a3 = fmaf(e2.w, wcol[q*16+11], a3);
            a0 = fmaf(e3.x, wcol[q*16+12], a0); a1 = fmaf(e3.y, wcol[q*16+13], a1);
            a2 = fmaf(e3.z, wcol[q*16+14], a2); a3 = fmaf(e3.w, wcol[q*16+15], a3);
        }
        xg_store(&xg[(size_t)(row0 + r) * G4 + tid], (a0 + a1) + (a2 + a3));
    }
}

// ---------------- Kernel 2: the sequential recurrence, one block per n ----------------
// grid 256, block 1024 (16 waves => VGPR cap 128; perpetual regs ~114).
// Histories (25 rows x2) + U columns (64) in registers. 4 barriers per step.
template <typename XGT>
__global__ __launch_bounds__(1024, 4) void k2_recur(
    const float* __restrict__ topo,     // (T, N, T)
    const float* __restrict__ mask,     // (T, N)
    const float* __restrict__ U,        // (H, 4H)
    const XGT* __restrict__ xg,         // (T*N, 4H)
    float* __restrict__ hmean)          // (N, H)
{
    const int n   = blockIdx.x;
    const int tid = threadIdx.x;
    const int g   = tid >> 7;           // 0..7 : owns rows t' == g (mod 8)
    const int h   = tid & 127;
    const int kh  = tid >> 9;           // 0..1 : K-half for phase B
    const int j   = tid & 511;          // gate column

    __shared__ __align__(16) float topoT[8][28]; // topoT[g][k] = topo[t][n][8k+g]
    __shared__ float part_h[8][HID];
    __shared__ float part_c[8][HID];
    __shared__ __align__(16) float hsum[HID];
    __shared__ float csum[HID];
    __shared__ float pB[2][G4];

    float ucol[64];
    #pragma unroll
    for (int hh = 0; hh < 64; ++hh) ucol[hh] = U[(size_t)(kh * 64 + hh) * G4 + j];

    float hreg[25], creg[25];
    #pragma unroll
    for (int k = 0; k < 25; ++k) { hreg[k] = 0.f; creg[k] = 0.f; }

    float hmacc = 0.f;
    float len = 0.f;

    for (int t = 0; t < TT; ++t) {
        const size_t rowbase = (size_t)t * NBATCH + n;
        // stage topo row transposed; prefetch x_gates row; uniform mask scalar
        if (tid < TT)            topoT[tid & 7][tid >> 3] = topo[rowbase * TT + tid];
        else if (tid < 224)      topoT[tid & 7][tid >> 3] = 0.f;
        const float m = mask[(size_t)t * NBATCH + n];
        const float xgv = (tid < G4) ? xg_load(&xg[rowbase * G4 + tid]) : 0.f;
        __syncthreads();                                   // (1)

        // phase A: partial weighted history sums (rows >= t hold zeros)
        float ah0 = 0.f, ah1 = 0.f, ac0 = 0.f, ac1 = 0.f;
        const float4* tp4 = (const float4*)&topoT[g][0];
        #pragma unroll
        for (int kk = 0; kk < 6; ++kk) {
            if (32 * kk < t) {   // uniform skip: chunk rows start at 32*kk+g
                float4 tp = tp4[kk];
                ah0 = fmaf(tp.x, hreg[4*kk+0], ah0);
                ac0 = fmaf(tp.x, creg[4*kk+0], ac0);
                ah1 = fmaf(tp.y, hreg[4*kk+1], ah1);
                ac1 = fmaf(tp.y, creg[4*kk+1], ac1);
                ah0 = fmaf(tp.z, hreg[4*kk+2], ah0);
                ac0 = fmaf(tp.z, creg[4*kk+2], ac0);
                ah1 = fmaf(tp.w, hreg[4*kk+3], ah1);
                ac1 = fmaf(tp.w, creg[4*kk+3], ac1);
            }
        }
        if (192 < t) {  // tail row k=24 (rows 192..199)
            const float tp = topoT[g][24];
            ah0 = fmaf(tp, hreg[24], ah0);
            ac0 = fmaf(tp, creg[24], ac0);
        }
        part_h[g][h] = ah0 + ah1;
        part_c[g][h] = ac0 + ac1;
        __syncthreads();                                   // (2)

        if (tid < HID) {
            float s = 0.f;
            #pragma unroll
            for (int gg = 0; gg < 8; ++gg) s += part_h[gg][tid];
            hsum[tid] = s;
        } else if (tid < 2 * HID) {
            const int hh = tid - HID;
            float s = 0.f;
            #pragma unroll
            for (int gg = 0; gg < 8; ++gg) s += part_c[gg][hh];
            csum[hh] = s;
        }
        __syncthreads();                                   // (3)

        // phase B: pB[kh][j] = sum_{hh<64} hsum[kh*64+hh]*U[kh*64+hh][j]  (+x_gates on kh=0)
        {
            float a0 = 0.f, a1 = 0.f, a2 = 0.f, a3 = 0.f;
            const float4* hs4 = (const float4*)&hsum[kh * 64];
            #pragma unroll
            for (int q = 0; q < 4; ++q) {
                float4 x0 = hs4[q*4+0], x1 = hs4[q*4+1], x2 = hs4[q*4+2], x3 = hs4[q*4+3];
                a0 = fmaf(x0.x, ucol[q*16+0],  a0); a1 = fmaf(x0.y, ucol[q*16+1],  a1);
                a2 = fmaf(x0.z, ucol[q*16+2],  a2); a3 = fmaf(x0.w, ucol[q*16+3],  a3);
                a0 = fmaf(x1.x, ucol[q*16+4],  a0); a1 = fmaf(x1.y, ucol[q*16+5],  a1);
                a2 = fmaf(x1.z, ucol[q*16+6],  a2); a3 = fmaf(x1.w, ucol[q*16+7],  a3);
                a0 = fmaf(x2.x, ucol[q*16+8],  a0); a1 = fmaf(x2.y, ucol[q*16+9],  a1);
                a2 = fmaf(x2.z, ucol[q*16+10], a2); a3 = fmaf(x2.w, ucol[q*16+11], a3);
                a0 = fmaf(x3.x, ucol[q*16+12], a0); a1 = fmaf(x3.y, ucol[q*16+13], a1);
                a2 = fmaf(x3.z, ucol[q*16+14], a2); a3 = fmaf(x3.w, ucol[q*16+15], a3);
            }
            pB[kh][j] = (a0 + a1) + (a2 + a3) + xgv;   // xgv == 0 for kh=1
        }
        __syncthreads();                                   // (4)

        // pointwise LSTM cell on owning group (t mod 8); precise transcendentals
        if (g == (t & 7)) {
            const float iv = pB[0][h]           + pB[1][h];
            const float fv = pB[0][HID + h]     + pB[1][HID + h];
            const float ov = pB[0][2 * HID + h] + pB[1][2 * HID + h];
            const float gv = pB[0][3 * HID + h] + pB[1][3 * HID + h];
            const float si = 1.f / (1.f + expf(-iv));
            const float sf = 1.f / (1.f + expf(-fv));
            const float so = 1.f / (1.f + expf(-ov));
            const float tg = tanhf(gv);
            const float cn = m * (sf * csum[h] + si * tg);
            const float hn = m * (so * tanhf(cn));
            const int kt = t >> 3;
            #pragma unroll
            for (int k = 0; k < 25; ++k) if (k == kt) { hreg[k] = hn; creg[k] = cn; }
            hmacc = fmaf(m, hn, hmacc);
        }
        len += m;
        // no barrier needed: all shared reads of this iter complete before the
        // barriers that precede any conflicting write in iter t+1
    }

    part_h[g][h] = hmacc;
    __syncthreads();
    if (tid < HID) {
        float s = 0.f;
        #pragma unroll
        for (int gg = 0; gg < 8; ++gg) s += part_h[gg][tid];
        hmean[(size_t)n * HID + tid] = s / len;
    }
}

// ---------------- Kernel 3: out = h_mean @ W_out + b_out ----------------
// grid (98, 4), block 512; 512 cols x 64 rows per block
__global__ __launch_bounds__(512, 2) void k3_out(
    const float* __restrict__ hm,      // (N, H)
    const float* __restrict__ Wout,    // (H, V)
    const float* __restrict__ bout,    // (V)
    float* __restrict__ out)           // (N, V)
{
    const int tid = threadIdx.x;
    const int v = blockIdx.x * 512 + tid;
    const int r0 = blockIdx.y * 64;
    __shared__ __align__(16) float hml[64][HID];
    {
        const int r = tid >> 3;        // 0..63
        const int c = tid & 7;         // 8 chunks of 16 floats
        const float4* src = (const float4*)(hm + (size_t)(r0 + r) * HID + c * 16);
        float4 a0 = src[0], a1 = src[1], a2 = src[2], a3 = src[3];
        float4* dst = (float4*)&hml[r][c * 16];
        dst[0] = a0; dst[1] = a1; dst[2] = a2; dst[3] = a3;
    }
    const int vc = v < VOC ? v : VOC - 1;
    float wcol[HID];
    #pragma unroll
    for (int h = 0; h < HID; ++h) wcol[h] = Wout[(size_t)h * VOC + vc];
    const float bj = bout[vc];
    __syncthreads();

    for (int r = 0; r < 64; ++r) {
        float a0 = bj, a1 = 0.f, a2 = 0.f, a3 = 0.f;
        const float4* hs4 = (const float4*)&hml[r][0];
        #pragma unroll
        for (int q = 0; q < 8; ++q) {
            float4 x0 = hs4[q*4+0], x1 = hs4[q*4+1], x2 = hs4[q*4+2], x3 = hs4[q*4+3];
            a0 = fmaf(x0.x, wcol[q*16+0],  a0); a1 = fmaf(x0.y, wcol[q*16+1],  a1);
            a2 = fmaf(x0.z, wcol[q*16+2],  a2); a3 = fmaf(x0.w, wcol[q*16+3],  a3);
            a0 = fmaf(x1.x, wcol[q*16+4],  a0); a1 = fmaf(x1.y, wcol[q*16+5],  a1);
            a2 = fmaf(x1.z, wcol[q*16+6],  a2); a3 = fmaf(x1.w, wcol[q*16+7],  a3);
            a0 = fmaf(x2.x, wcol[q*16+8],  a0); a1 = fmaf(x2.y, wcol[q*16+9],  a1);
            a2 = fmaf(x2.z, wcol[q*16+10], a2); a3 = fmaf(x2.w, wcol[q*16+11], a3);
            a0 = fmaf(x3.x, wcol[q*16+12], a0); a1 = fmaf(x3.y, wcol[q*16+13], a1);
            a2 = fmaf(x3.z, wcol[q*16+14], a2); a3 = fmaf(x3.w, wcol[q*16+15], a3);
        }
        if (v < VOC) out[(size_t)(r0 + r) * VOC + v] = (a0 + a1) + (a2 + a3);
    }
}

extern "C" void kernel_launch(void* const* d_in, const int* in_sizes, int n_in,
                              void* d_out, int out_size, void* d_ws, size_t ws_size,
                              hipStream_t stream) {
    const int*   seq  = (const int*)d_in[0];     // (T,N) int32
    const float* msk  = (const float*)d_in[1];   // (T,N)
    const float* topo = (const float*)d_in[2];   // (T,N,T)
    const float* W    = (const float*)d_in[3];   // (H,4H)
    const float* U    = (const float*)d_in[4];   // (H,4H)
    const float* b    = (const float*)d_in[5];   // (4H)
    const float* ET   = (const float*)d_in[6];   // (V,H)
    const float* Wout = (const float*)d_in[7];   // (H,V)
    const float* bout = (const float*)d_in[8];   // (V)
    float* out = (float*)d_out;

    const size_t xg_elems = (size_t)TT * NBATCH * G4;
    const size_t need_f32 = xg_elems * sizeof(float) + (size_t)NBATCH * HID * sizeof(float);

    if (ws_size >= need_f32) {
        // primary path: fp32 x_gates (104.9 MB) — keeps recurrence noise at fp32 level
        float* xg = (float*)d_ws;
        float* hmean = (float*)((char*)d_ws + xg_elems * sizeof(float));
        k1_xgates<float><<<1600, 512, 0, stream>>>(seq, ET, W, b, xg);
        k2_recur<float><<<NBATCH, 1024, 0, stream>>>(topo, msk, U, xg, hmean);
        k3_out<<<dim3(98, 4), 512, 0, stream>>>(hmean, Wout, bout, out);
    } else {
        // fallback: bf16 x_gates (52.4 MB) — memory-safe even if ws is small
        __hip_bfloat16* xg = (__hip_bfloat16*)d_ws;
        float* hmean = (float*)((char*)d_ws + xg_elems * sizeof(__hip_bfloat16));
        k1_xgates<__hip_bfloat16><<<1600, 512, 0, stream>>>(seq, ET, W, b, xg);
        k2_recur<__hip_bfloat16><<<NBATCH, 1024, 0, stream>>>(topo, msk, U, xg, hmean);
        k3_out<<<dim3(98, 4), 512, 0, stream>>>(hmean, Wout, bout, out);
    }
}

// Round 3
// 2034.957 us; speedup vs baseline: 1.1790x; 1.1790x over previous
//
#include <hip/hip_runtime.h>
#include <hip/hip_bf16.h>

#define TT 200
#define NBATCH 256
#define HID 128
#define G4 512
#define VOC 50000

// ---------------- Kernel 1: x_gates = gather(ET, seq) @ W + b (fp32!) ----------------
// bf16 x_gates empirically fatal (R0: absmax 0.656) — recurrence amplifies noise.
// grid 1600, block 512; 32 rows per block. launch_bounds(512,1) => VGPR cap 256.
__global__ __launch_bounds__(512, 1) void k1_xgates(
    const int* __restrict__ seq,        // (T*N)
    const float* __restrict__ ET,       // (V, H)
    const float* __restrict__ W,        // (H, 4H)
    const float* __restrict__ b,        // (4H)
    float* __restrict__ xg)             // (T*N, 4H)
{
    const int tid = threadIdx.x;
    const int row0 = blockIdx.x * 32;
    __shared__ int idx[32];
    __shared__ __align__(16) float emb[32][HID];
    if (tid < 32) idx[tid] = seq[row0 + tid];
    __syncthreads();
    {
        const int r = tid >> 4;        // 0..31
        const int c = tid & 15;        // 16 chunks of 8 floats
        const float* src = ET + (size_t)idx[r] * HID + c * 8;
        float4 v0 = ((const float4*)src)[0];
        float4 v1 = ((const float4*)src)[1];
        ((float4*)&emb[r][c * 8])[0] = v0;
        ((float4*)&emb[r][c * 8])[1] = v1;
    }
    float wcol[HID];
    #pragma unroll
    for (int h = 0; h < HID; ++h) wcol[h] = W[(size_t)h * G4 + tid];
    const float bj = b[tid];
    __syncthreads();

    for (int r = 0; r < 32; ++r) {
        float a0 = bj, a1 = 0.f, a2 = 0.f, a3 = 0.f;
        const float4* e4 = (const float4*)&emb[r][0];
        #pragma unroll
        for (int q = 0; q < 32; ++q) {
            float4 e = e4[q];
            a0 = fmaf(e.x, wcol[4*q+0], a0);
            a1 = fmaf(e.y, wcol[4*q+1], a1);
            a2 = fmaf(e.z, wcol[4*q+2], a2);
            a3 = fmaf(e.w, wcol[4*q+3], a3);
        }
        xg[(size_t)(row0 + r) * G4 + tid] = (a0 + a1) + (a2 + a3);
    }
}

// ---------------- Kernel 2: sequential recurrence, one block of 512 per n ----------------
// 512 threads = 8 waves = 2 waves/SIMD => VGPR cap 256. Perpetual regs:
// ucol[128] + hreg[50] + creg[50] = 228 (+ ~20 temps) -> fits, NO SPILLS (the R1 killer).
// 4 groups: group g owns history rows t' == g (mod 4). 4 barriers/step.
__global__ __launch_bounds__(512, 1) void k2_recur(
    const float* __restrict__ topo,     // (T, N, T)
    const float* __restrict__ mask,     // (T, N)
    const float* __restrict__ U,        // (H, 4H)
    const float* __restrict__ xg,       // (T*N, 4H) fp32
    float* __restrict__ hmean)          // (N, H)
{
    const int n   = blockIdx.x;
    const int tid = threadIdx.x;
    const int g   = tid >> 7;           // 0..3 (wave-uniform)
    const int h   = tid & 127;

    __shared__ __align__(16) float topoT[4][52]; // topoT[g][k] = topo[t][n][4k+g]; row=208B (16B-aligned)
    __shared__ float part_h[4][HID];
    __shared__ float part_c[4][HID];
    __shared__ __align__(16) float hsum[HID];
    __shared__ float csum[HID];
    __shared__ float gates[G4];

    // each thread: full K=128 U column for gate column j=tid
    float ucol[128];
    #pragma unroll
    for (int k = 0; k < 128; ++k) ucol[k] = U[(size_t)k * G4 + tid];

    float hreg[50], creg[50];
    #pragma unroll
    for (int k = 0; k < 50; ++k) { hreg[k] = 0.f; creg[k] = 0.f; }

    float hmacc = 0.f;
    float len = 0.f;

    for (int t = 0; t < TT; ++t) {
        const size_t rowbase = (size_t)t * NBATCH + n;
        if (tid < TT) topoT[tid & 3][tid >> 2] = topo[rowbase * TT + tid];
        const float m = mask[(size_t)t * NBATCH + n];
        const float xgv = xg[rowbase * G4 + tid];
        __syncthreads();                                   // (1)

        // phase A: weighted history partials; rows >= t hold zeros (guards are perf-only)
        float ah0 = 0.f, ah1 = 0.f, ac0 = 0.f, ac1 = 0.f;
        const float4* tp4 = (const float4*)&topoT[g][0];   // broadcast reads (uniform per wave)
        #pragma unroll
        for (int kk = 0; kk < 12; ++kk) {
            if (16 * kk < t) {      // chunk rows start at 16*kk+g
                float4 tp = tp4[kk];
                ah0 = fmaf(tp.x, hreg[4*kk+0], ah0);
                ac0 = fmaf(tp.x, creg[4*kk+0], ac0);
                ah1 = fmaf(tp.y, hreg[4*kk+1], ah1);
                ac1 = fmaf(tp.y, creg[4*kk+1], ac1);
                ah0 = fmaf(tp.z, hreg[4*kk+2], ah0);
                ac0 = fmaf(tp.z, creg[4*kk+2], ac0);
                ah1 = fmaf(tp.w, hreg[4*kk+3], ah1);
                ac1 = fmaf(tp.w, creg[4*kk+3], ac1);
            }
        }
        if (192 < t) {  // tail k=48,49 (rows 192..199)
            const float tpx = topoT[g][48];
            const float tpy = topoT[g][49];
            ah0 = fmaf(tpx, hreg[48], ah0);
            ac0 = fmaf(tpx, creg[48], ac0);
            ah1 = fmaf(tpy, hreg[49], ah1);
            ac1 = fmaf(tpy, creg[49], ac1);
        }
        part_h[g][h] = ah0 + ah1;
        part_c[g][h] = ac0 + ac1;
        __syncthreads();                                   // (2)

        if (tid < HID) {
            hsum[tid] = ((part_h[0][tid] + part_h[1][tid]) +
                         (part_h[2][tid] + part_h[3][tid]));
        } else if (tid < 2 * HID) {
            const int hh = tid - HID;
            csum[hh] = ((part_c[0][hh] + part_c[1][hh]) +
                        (part_c[2][hh] + part_c[3][hh]));
        }
        __syncthreads();                                   // (3)

        // phase B: gates[j] = hsum . U[:,j] + x_gates[j]
        {
            float a0 = 0.f, a1 = 0.f, a2 = 0.f, a3 = 0.f;
            const float4* hs4 = (const float4*)hsum;       // broadcast b128 reads
            #pragma unroll
            for (int q = 0; q < 32; ++q) {
                float4 x = hs4[q];
                a0 = fmaf(x.x, ucol[4*q+0], a0);
                a1 = fmaf(x.y, ucol[4*q+1], a1);
                a2 = fmaf(x.z, ucol[4*q+2], a2);
                a3 = fmaf(x.w, ucol[4*q+3], a3);
            }
            gates[tid] = (a0 + a1) + (a2 + a3) + xgv;
        }
        __syncthreads();                                   // (4)

        // pointwise cell on owning group (wave-uniform branch); precise transcendentals
        if (g == (t & 3)) {
            const float iv = gates[h];
            const float fv = gates[HID + h];
            const float ov = gates[2 * HID + h];
            const float gv = gates[3 * HID + h];
            const float si = 1.f / (1.f + expf(-iv));
            const float sf = 1.f / (1.f + expf(-fv));
            const float so = 1.f / (1.f + expf(-ov));
            const float tg = tanhf(gv);
            const float cn = m * (sf * csum[h] + si * tg);
            const float hn = m * (so * tanhf(cn));
            const int kt = t >> 2;
            #pragma unroll
            for (int k = 0; k < 50; ++k) if (k == kt) { hreg[k] = hn; creg[k] = cn; }
            hmacc = fmaf(m, hn, hmacc);
        }
        len += m;
        // safe: every later write to {topoT,part,hsum,csum,gates} is separated from
        // this iteration's reads by at least one intervening barrier
    }

    part_h[g][h] = hmacc;
    __syncthreads();
    if (tid < HID) {
        const float s = ((part_h[0][tid] + part_h[1][tid]) +
                         (part_h[2][tid] + part_h[3][tid]));
        hmean[(size_t)n * HID + tid] = s / len;
    }
}

// ---------------- Kernel 3: out = h_mean @ W_out + b_out ----------------
// grid (98, 4), block 512; 512 cols x 64 rows per block. launch_bounds(512,1) => no spills.
__global__ __launch_bounds__(512, 1) void k3_out(
    const float* __restrict__ hm,      // (N, H)
    const float* __restrict__ Wout,    // (H, V)
    const float* __restrict__ bout,    // (V)
    float* __restrict__ out)           // (N, V)
{
    const int tid = threadIdx.x;
    const int v = blockIdx.x * 512 + tid;
    const int r0 = blockIdx.y * 64;
    __shared__ __align__(16) float hml[64][HID];
    {
        const int r = tid >> 3;        // 0..63
        const int c = tid & 7;         // 8 chunks of 16 floats
        const float4* src = (const float4*)(hm + (size_t)(r0 + r) * HID + c * 16);
        float4 a0 = src[0], a1 = src[1], a2 = src[2], a3 = src[3];
        float4* dst = (float4*)&hml[r][c * 16];
        dst[0] = a0; dst[1] = a1; dst[2] = a2; dst[3] = a3;
    }
    const int vc = v < VOC ? v : VOC - 1;
    float wcol[HID];
    #pragma unroll
    for (int h = 0; h < HID; ++h) wcol[h] = Wout[(size_t)h * VOC + vc];
    const float bj = bout[vc];
    __syncthreads();

    for (int r = 0; r < 64; ++r) {
        float a0 = bj, a1 = 0.f, a2 = 0.f, a3 = 0.f;
        const float4* hs4 = (const float4*)&hml[r][0];
        #pragma unroll
        for (int q = 0; q < 32; ++q) {
            float4 x = hs4[q];
            a0 = fmaf(x.x, wcol[4*q+0], a0);
            a1 = fmaf(x.y, wcol[4*q+1], a1);
            a2 = fmaf(x.z, wcol[4*q+2], a2);
            a3 = fmaf(x.w, wcol[4*q+3], a3);
        }
        if (v < VOC) out[(size_t)(r0 + r) * VOC + v] = (a0 + a1) + (a2 + a3);
    }
}

extern "C" void kernel_launch(void* const* d_in, const int* in_sizes, int n_in,
                              void* d_out, int out_size, void* d_ws, size_t ws_size,
                              hipStream_t stream) {
    const int*   seq  = (const int*)d_in[0];     // (T,N) int32
    const float* msk  = (const float*)d_in[1];   // (T,N)
    const float* topo = (const float*)d_in[2];   // (T,N,T)
    const float* W    = (const float*)d_in[3];   // (H,4H)
    const float* U    = (const float*)d_in[4];   // (H,4H)
    const float* b    = (const float*)d_in[5];   // (4H)
    const float* ET   = (const float*)d_in[6];   // (V,H)
    const float* Wout = (const float*)d_in[7];   // (H,V)
    const float* bout = (const float*)d_in[8];   // (V)
    float* out = (float*)d_out;

    const size_t xg_elems = (size_t)TT * NBATCH * G4;
    float* xg = (float*)d_ws;                                  // 104.9 MB fp32
    float* hmean = (float*)((char*)d_ws + xg_elems * sizeof(float));

    k1_xgates<<<1600, 512, 0, stream>>>(seq, ET, W, b, xg);
    k2_recur<<<NBATCH, 512, 0, stream>>>(topo, msk, U, xg, hmean);
    k3_out<<<dim3(98, 4), 512, 0, stream>>>(hmean, Wout, bout, out);
}